// Round 11
// baseline (501.395 us; speedup 1.0000x reference)
//
#include <hip/hip_runtime.h>

#define NTOTAL 100000
#define NNODES 16384
#define K 32
#define S 16
#define D 190
#define E 64
#define NREL 3

__device__ float g_invn[NTOTAL];
__device__ float g_wa[384];    // [0..191] = W@a1, [192..383] = W@a2 (190,191 zeroed)

// ---------- pad+norm: features -> ws rows of PR floats; invn -> g_invn ----------
template <int PR>
__global__ __launch_bounds__(256) void pad_kernel(const float* __restrict__ features,
                                                  float* __restrict__ pf) {
    const int row  = blockIdx.x * 4 + (threadIdx.x >> 6);
    const int lane = threadIdx.x & 63;
    if (row >= NTOTAL) return;
    const float2* rp = (const float2*)(features + (size_t)row * D);
    float2 lo = rp[lane];
    float2 hi = make_float2(0.f, 0.f);
    if (lane < 31) hi = rp[64 + lane];                   // floats 128..189
    float ss = fmaf(lo.x, lo.x, fmaf(lo.y, lo.y, fmaf(hi.x, hi.x, hi.y * hi.y)));
    #pragma unroll
    for (int off = 32; off; off >>= 1) ss += __shfl_xor(ss, off, 64);
    float2* wp = (float2*)(pf + (size_t)row * PR);
    wp[lane] = lo;                                       // slots 0..63
    if (lane < 31) wp[64 + lane] = hi;                   // slots 64..94
    if (lane == 31) wp[95] = make_float2(0.f, 0.f);      // floats 190,191 = 0
    if (lane == 0)  g_invn[row] = 1.0f / sqrtf(ss);
}

// ---------- norms only (unpadded fallback path) ----------
__global__ __launch_bounds__(256) void norms_kernel(const float* __restrict__ features) {
    const int row  = blockIdx.x * 4 + (threadIdx.x >> 6);
    const int lane = threadIdx.x & 63;
    if (row >= NTOTAL) return;
    const float2* rp = (const float2*)(features + (size_t)row * D);
    float2 a = rp[lane];
    float ss = fmaf(a.x, a.x, a.y * a.y);
    if (lane < 31) {
        float2 b = rp[64 + lane];
        ss = fmaf(b.x, b.x, fmaf(b.y, b.y, ss));
    }
    #pragma unroll
    for (int off = 32; off; off >>= 1) ss += __shfl_xor(ss, off, 64);
    if (lane == 0) g_invn[row] = 1.0f / sqrtf(ss);
}

// ---------- wa1 = W@a1, wa2 = W@a2 ----------
__global__ __launch_bounds__(192) void prep_wa(const float* __restrict__ weight,
                                               const float* __restrict__ avec) {
    const int d = threadIdx.x;              // 0..191
    float s1 = 0.f, s2 = 0.f;
    if (d < D) {
        const float* wr = weight + d * E;
        #pragma unroll 8
        for (int e = 0; e < E; ++e) {
            const float w = wr[e];
            s1 = fmaf(w, avec[e],     s1);
            s2 = fmaf(w, avec[E + e], s2);
        }
    }
    g_wa[d]       = s1;
    g_wa[192 + d] = s2;
}

// ---------- PADDED main: 4-row bursts, SGPR row bases, 64-VGPR tier ----------
// Lane layout: lo = slot `lane` (dims 0..127); hi = slot 64+(lane&31)
// (dims 128..191; 190,191 stored zeros). Lanes 32..63 read duplicate hi slots
// (same cache lines); their center-hi c1 is zeroed so contributions vanish.
// (256,8) targets the <=64-VGPR tier (32 waves/CU); burst=4 + readfirstlane
// scalar bases shrink the working set to ~60 so the cap should NOT spill
// (WRITE_SIZE is the detector; R5/6/7 spilled because cap << working set).
template <int PR>
__global__ __launch_bounds__(256, 8) void interagg_pad(
    const float* __restrict__ pf,         // [NTOTAL, PR] padded
    const int*   __restrict__ nodes,
    const int*   __restrict__ neigh1,
    const int*   __restrict__ neigh2,
    const int*   __restrict__ neigh3,
    const float* __restrict__ weight,     // [D, E]
    float*       __restrict__ out)        // [N, E]
{
    __shared__ int   s_idx[4][96];
    __shared__ float s_sim[4][32];
    __shared__ __align__(16) float s_v[4][192];

    const int t    = threadIdx.x;
    const int lane = t & 63;
    const int wave = t >> 6;
    const int n    = blockIdx.x * 4 + wave;

    int*   idxw = s_idx[wave];
    float* simw = s_sim[wave];
    float* vw   = s_v[wave];

    {
        const int v1 = (lane < 32) ? neigh1[n * K + lane] : neigh2[n * K + (lane - 32)];
        idxw[lane] = v1;
        if (lane < 32) idxw[64 + lane] = neigh3[n * K + lane];
    }

    const int  crow = nodes[n];
    const int  hs   = 64 + (lane & 31);            // hi float2 slot (64..95)
    const bool hiok = (lane < 32);
    const float2* crp = (const float2*)(pf + (size_t)crow * PR);
    float2 c0 = crp[lane];
    float2 c1 = crp[hs];
    if (!hiok) { c1.x = 0.f; c1.y = 0.f; }         // lanes 32-63: duplicates, masked

    float rlx[NREL], rly[NREL], rhx[NREL], rhy[NREL];

    #pragma unroll
    for (int rel = 0; rel < NREL; ++rel) {
        const int* idz = idxw + rel * 32;

        // ---- sims: 8 bursts of 4 rows; SGPR base per row (rid wave-uniform) ----
        #pragma unroll
        for (int b = 0; b < 8; ++b) {
            float2 va[4], vb[4];
            float  dt[4];
            #pragma unroll
            for (int i = 0; i < 4; ++i) {
                const int rid = __builtin_amdgcn_readfirstlane(idz[b * 4 + i]);
                const float2* rp = (const float2*)(pf + (size_t)rid * PR);
                va[i] = rp[lane];
                vb[i] = rp[hs];
            }
            #pragma unroll
            for (int i = 0; i < 4; ++i)
                dt[i] = fmaf(c0.x, va[i].x, fmaf(c0.y, va[i].y,
                        fmaf(c1.x, vb[i].x, c1.y * vb[i].y)));
            #pragma unroll
            for (int off = 32; off; off >>= 1) {
                #pragma unroll
                for (int i = 0; i < 4; ++i)
                    dt[i] += __shfl_xor(dt[i], off, 64);
            }
            if (lane == 0) {
                #pragma unroll
                for (int i = 0; i < 4; ++i)
                    simw[b * 4 + i] = dt[i];
            }
        }

        // ---- scale by 1/||nf||: 32 parallel per-lane gathers ----
        if (lane < 32) simw[lane] *= g_invn[idz[lane]];

        // ---- top-S by rank via shuffles (ties -> lower index, as lax.top_k) ----
        const float sk = simw[lane & 31];
        int rank = (lane < 32) ? 0 : 64;
        #pragma unroll
        for (int j = 0; j < K; ++j) {
            const float sj = __shfl(sk, j, 64);
            rank += (sj > sk) || (sj == sk && j < lane);
        }
        unsigned int m = (unsigned int)__ballot(rank < S);

        // ---- mean of 16 selected rows: 4 bursts of 4 (L2-hot re-gather) ----
        float2 acc_lo = make_float2(0.f, 0.f);
        float2 acc_hi = make_float2(0.f, 0.f);
        #pragma unroll
        for (int q = 0; q < 4; ++q) {
            float2 ua[4], ub[4];
            #pragma unroll
            for (int i = 0; i < 4; ++i) {
                const int k = __ffs(m) - 1; m &= m - 1;
                const int rid = __builtin_amdgcn_readfirstlane(idz[k]);
                const float2* rp = (const float2*)(pf + (size_t)rid * PR);
                ua[i] = rp[lane];
                ub[i] = rp[hs];
            }
            #pragma unroll
            for (int i = 0; i < 4; ++i) {
                acc_lo.x += ua[i].x; acc_lo.y += ua[i].y;
                acc_hi.x += ub[i].x; acc_hi.y += ub[i].y;
            }
        }
        rlx[rel] = fmaxf(acc_lo.x * (1.f / S), 0.f);
        rly[rel] = fmaxf(acc_lo.y * (1.f / S), 0.f);
        rhx[rel] = fmaxf(acc_hi.x * (1.f / S), 0.f);      // lanes>=32: dup data, unused
        rhy[rel] = fmaxf(acc_hi.y * (1.f / S), 0.f);
    }

    // ---- attention scores: e_r = center.wa1 + rmean_r.wa2 ----
    const float2* gw1 = (const float2*)g_wa;
    const float2* gw2 = (const float2*)(g_wa + 192);
    float2 w1l = gw1[lane];
    float2 w1h = gw1[hs];                                 // slots 190,191 = 0
    float2 w2l = gw2[lane];
    float2 w2h = gw2[hs];
    if (!hiok) { w1h.x = w1h.y = 0.f; w2h.x = w2h.y = 0.f; }

    float dv[4];
    dv[0] = fmaf(c0.x, w1l.x, fmaf(c0.y, w1l.y, fmaf(c1.x, w1h.x, c1.y * w1h.y)));
    #pragma unroll
    for (int r = 0; r < NREL; ++r)
        dv[1 + r] = fmaf(rlx[r], w2l.x, fmaf(rly[r], w2l.y,
                    fmaf(rhx[r], w2h.x, rhy[r] * w2h.y)));
    #pragma unroll
    for (int off = 32; off; off >>= 1) {
        #pragma unroll
        for (int i = 0; i < 4; ++i)
            dv[i] += __shfl_xor(dv[i], off, 64);
    }

    float e1 = dv[0] + dv[1], e2 = dv[0] + dv[2], e3 = dv[0] + dv[3];
    e1 = (e1 >= 0.f) ? e1 : 0.2f * e1;
    e2 = (e2 >= 0.f) ? e2 : 0.2f * e2;
    e3 = (e3 >= 0.f) ? e3 : 0.2f * e3;
    const float mx  = fmaxf(e1, fmaxf(e2, e3));
    const float x1 = expf(e1 - mx), x2 = expf(e2 - mx), x3 = expf(e3 - mx);
    const float inv = 1.f / (x1 + x2 + x3);
    const float a1w = x1 * inv, a2w = x2 * inv, a3w = x3 * inv;

    // ---- v = center + sum att_r * rmean_r ; out = relu(v @ W) ----
    float2 v_lo, v_hi;
    v_lo.x = fmaf(a1w, rlx[0], fmaf(a2w, rlx[1], fmaf(a3w, rlx[2], c0.x)));
    v_lo.y = fmaf(a1w, rly[0], fmaf(a2w, rly[1], fmaf(a3w, rly[2], c0.y)));
    v_hi.x = fmaf(a1w, rhx[0], fmaf(a2w, rhx[1], fmaf(a3w, rhx[2], c1.x)));
    v_hi.y = fmaf(a1w, rhy[0], fmaf(a2w, rhy[1], fmaf(a3w, rhy[2], c1.y)));

    ((float2*)vw)[lane] = v_lo;
    if (hiok) ((float2*)vw)[64 + lane] = v_hi;            // lane31 writes zeros to 190,191

    float acc = 0.f;
    const float* wcol = weight + lane;
    #pragma unroll 4
    for (int d4 = 0; d4 < 47; ++d4) {                     // dims 0..187
        const float4 vv = *((const float4*)vw + d4);      // uniform b128 broadcast
        const int d = d4 * 4;
        acc = fmaf(vv.x, wcol[(d    ) * E], acc);
        acc = fmaf(vv.y, wcol[(d + 1) * E], acc);
        acc = fmaf(vv.z, wcol[(d + 2) * E], acc);
        acc = fmaf(vv.w, wcol[(d + 3) * E], acc);
    }
    {                                                     // dims 188,189
        const float2 vv2 = *((const float2*)vw + 94);
        acc = fmaf(vv2.x, wcol[188 * E], acc);
        acc = fmaf(vv2.y, wcol[189 * E], acc);
    }
    out[(size_t)n * E + lane] = fmaxf(acc, 0.f);
}

// ---------- FALLBACK main (R8 verbatim): unpadded reads + g_invn table ----------
__global__ __launch_bounds__(256) void interagg_wave(
    const float* __restrict__ features,
    const int*   __restrict__ nodes,
    const int*   __restrict__ neigh1,
    const int*   __restrict__ neigh2,
    const int*   __restrict__ neigh3,
    const float* __restrict__ weight,
    float*       __restrict__ out)
{
    __shared__ int   s_idx[4][96];
    __shared__ float s_sim[4][32];
    __shared__ __align__(16) float s_v[4][192];

    const int t    = threadIdx.x;
    const int lane = t & 63;
    const int wave = t >> 6;
    const int n    = blockIdx.x * 4 + wave;

    int*   idxw = s_idx[wave];
    float* simw = s_sim[wave];
    float* vw   = s_v[wave];

    {
        const int v1 = (lane < 32) ? neigh1[n * K + lane] : neigh2[n * K + (lane - 32)];
        idxw[lane] = v1;
        if (lane < 32) idxw[64 + lane] = neigh3[n * K + lane];
    }

    const int  crow = nodes[n];
    const int  hl   = (lane < 31) ? lane : 30;
    const bool hiok = (lane < 31);
    const float2* crp = (const float2*)(features + (size_t)crow * D);
    float2 c0 = crp[lane];
    float2 c1 = crp[64 + hl];
    if (!hiok) { c1.x = 0.f; c1.y = 0.f; }

    float rlx[NREL], rly[NREL], rhx[NREL], rhy[NREL];

    #pragma unroll
    for (int rel = 0; rel < NREL; ++rel) {
        const int* idz = idxw + rel * 32;
        #pragma unroll
        for (int b = 0; b < 4; ++b) {
            float2 va[8], vb[8];
            float  dt[8];
            #pragma unroll
            for (int i = 0; i < 8; ++i) {
                const int rid = idz[b * 8 + i];
                const float2* rp = (const float2*)(features + (size_t)rid * D);
                va[i] = rp[lane];
                vb[i] = rp[64 + hl];
            }
            #pragma unroll
            for (int i = 0; i < 8; ++i)
                dt[i] = fmaf(c0.x, va[i].x, fmaf(c0.y, va[i].y,
                        fmaf(c1.x, vb[i].x, c1.y * vb[i].y)));
            #pragma unroll
            for (int off = 32; off; off >>= 1) {
                #pragma unroll
                for (int i = 0; i < 8; ++i)
                    dt[i] += __shfl_xor(dt[i], off, 64);
            }
            if (lane == 0) {
                #pragma unroll
                for (int i = 0; i < 8; ++i)
                    simw[b * 8 + i] = dt[i];
            }
        }
        if (lane < 32) simw[lane] *= g_invn[idz[lane]];

        const float sk = simw[lane & 31];
        int rank = (lane < 32) ? 0 : 64;
        #pragma unroll
        for (int j = 0; j < K; ++j) {
            const float sj = __shfl(sk, j, 64);
            rank += (sj > sk) || (sj == sk && j < lane);
        }
        unsigned int m = (unsigned int)__ballot(rank < S);

        float2 acc_lo = make_float2(0.f, 0.f);
        float2 acc_hi = make_float2(0.f, 0.f);
        #pragma unroll
        for (int half = 0; half < 2; ++half) {
            float2 ua[8], ub[8];
            #pragma unroll
            for (int i = 0; i < 8; ++i) {
                const int k = __ffs(m) - 1; m &= m - 1;
                const int rid = idz[k];
                const float2* rp = (const float2*)(features + (size_t)rid * D);
                ua[i] = rp[lane];
                ub[i] = rp[64 + hl];
            }
            #pragma unroll
            for (int i = 0; i < 8; ++i) {
                acc_lo.x += ua[i].x; acc_lo.y += ua[i].y;
                acc_hi.x += ub[i].x; acc_hi.y += ub[i].y;
            }
        }
        rlx[rel] = fmaxf(acc_lo.x * (1.f / S), 0.f);
        rly[rel] = fmaxf(acc_lo.y * (1.f / S), 0.f);
        rhx[rel] = fmaxf(acc_hi.x * (1.f / S), 0.f);
        rhy[rel] = fmaxf(acc_hi.y * (1.f / S), 0.f);
    }

    float2 w1l = ((const float2*)g_wa)[lane];
    float2 w1h = ((const float2*)g_wa)[64 + hl];
    float2 w2l = ((const float2*)(g_wa + 192))[lane];
    float2 w2h = ((const float2*)(g_wa + 192))[64 + hl];
    if (!hiok) { w1h.x = w1h.y = 0.f; w2h.x = w2h.y = 0.f; }

    float dv[4];
    dv[0] = fmaf(c0.x, w1l.x, fmaf(c0.y, w1l.y, fmaf(c1.x, w1h.x, c1.y * w1h.y)));
    #pragma unroll
    for (int r = 0; r < NREL; ++r)
        dv[1 + r] = fmaf(rlx[r], w2l.x, fmaf(rly[r], w2l.y,
                    fmaf(rhx[r], w2h.x, rhy[r] * w2h.y)));
    #pragma unroll
    for (int off = 32; off; off >>= 1) {
        #pragma unroll
        for (int i = 0; i < 4; ++i)
            dv[i] += __shfl_xor(dv[i], off, 64);
    }

    float e1 = dv[0] + dv[1], e2 = dv[0] + dv[2], e3 = dv[0] + dv[3];
    e1 = (e1 >= 0.f) ? e1 : 0.2f * e1;
    e2 = (e2 >= 0.f) ? e2 : 0.2f * e2;
    e3 = (e3 >= 0.f) ? e3 : 0.2f * e3;
    const float mx  = fmaxf(e1, fmaxf(e2, e3));
    const float x1 = expf(e1 - mx), x2 = expf(e2 - mx), x3 = expf(e3 - mx);
    const float inv = 1.f / (x1 + x2 + x3);
    const float a1w = x1 * inv, a2w = x2 * inv, a3w = x3 * inv;

    float2 v_lo, v_hi;
    v_lo.x = fmaf(a1w, rlx[0], fmaf(a2w, rlx[1], fmaf(a3w, rlx[2], c0.x)));
    v_lo.y = fmaf(a1w, rly[0], fmaf(a2w, rly[1], fmaf(a3w, rly[2], c0.y)));
    v_hi.x = fmaf(a1w, rhx[0], fmaf(a2w, rhx[1], fmaf(a3w, rhx[2], c1.x)));
    v_hi.y = fmaf(a1w, rhy[0], fmaf(a2w, rhy[1], fmaf(a3w, rhy[2], c1.y)));

    ((float2*)vw)[lane] = v_lo;
    if (hiok) ((float2*)vw)[64 + lane] = v_hi;

    float acc = 0.f;
    const float* wcol = weight + lane;
    #pragma unroll 4
    for (int d4 = 0; d4 < 47; ++d4) {
        const float4 vv = *((const float4*)vw + d4);
        const int d = d4 * 4;
        acc = fmaf(vv.x, wcol[(d    ) * E], acc);
        acc = fmaf(vv.y, wcol[(d + 1) * E], acc);
        acc = fmaf(vv.z, wcol[(d + 2) * E], acc);
        acc = fmaf(vv.w, wcol[(d + 3) * E], acc);
    }
    {
        const float2 vv2 = *((const float2*)vw + 94);
        acc = fmaf(vv2.x, wcol[188 * E], acc);
        acc = fmaf(vv2.y, wcol[189 * E], acc);
    }
    out[(size_t)n * E + lane] = fmaxf(acc, 0.f);
}

extern "C" void kernel_launch(void* const* d_in, const int* in_sizes, int n_in,
                              void* d_out, int out_size, void* d_ws, size_t ws_size,
                              hipStream_t stream) {
    const float* features = (const float*)d_in[0];
    const int*   nodes    = (const int*)  d_in[1];
    const int*   neigh1   = (const int*)  d_in[2];
    const int*   neigh2   = (const int*)  d_in[3];
    const int*   neigh3   = (const int*)  d_in[4];
    const float* weight   = (const float*)d_in[5];
    const float* avec     = (const float*)d_in[6];
    float*       out      = (float*)d_out;

    prep_wa<<<1, 192, 0, stream>>>(weight, avec);

    if (ws_size >= (size_t)NTOTAL * 224 * sizeof(float)) {
        // 896B stride: rows line-aligned, exactly 6 lines touched, line stride 7
        // (coprime with pow2) -> uniform L1/L2 set & channel distribution.
        float* pf = (float*)d_ws;
        pad_kernel<224><<<(NTOTAL + 3) / 4, 256, 0, stream>>>(features, pf);
        interagg_pad<224><<<NNODES / 4, 256, 0, stream>>>(
            pf, nodes, neigh1, neigh2, neigh3, weight, out);
    } else if (ws_size >= (size_t)NTOTAL * 192 * sizeof(float)) {
        float* pf = (float*)d_ws;
        pad_kernel<192><<<(NTOTAL + 3) / 4, 256, 0, stream>>>(features, pf);
        interagg_pad<192><<<NNODES / 4, 256, 0, stream>>>(
            pf, nodes, neigh1, neigh2, neigh3, weight, out);
    } else {
        norms_kernel<<<(NTOTAL + 3) / 4, 256, 0, stream>>>(features);
        interagg_wave<<<NNODES / 4, 256, 0, stream>>>(
            features, nodes, neigh1, neigh2, neigh3, weight, out);
    }
}

// Round 12
// 389.594 us; speedup vs baseline: 1.2870x; 1.2870x over previous
//
#include <hip/hip_runtime.h>

#define NTOTAL 100000
#define NNODES 16384
#define K 32
#define S 16
#define D 190
#define E 64
#define NREL 3

__device__ float g_invn[NTOTAL];
__device__ float g_wa[384];    // [0..191] = W@a1, [192..383] = W@a2 (190,191 zeroed)

// ---------- pad+norm: features -> ws rows of PR floats; invn -> g_invn ----------
template <int PR>
__global__ __launch_bounds__(256) void pad_kernel(const float* __restrict__ features,
                                                  float* __restrict__ pf) {
    const int row  = blockIdx.x * 4 + (threadIdx.x >> 6);
    const int lane = threadIdx.x & 63;
    if (row >= NTOTAL) return;
    const float2* rp = (const float2*)(features + (size_t)row * D);
    float2 lo = rp[lane];
    float2 hi = make_float2(0.f, 0.f);
    if (lane < 31) hi = rp[64 + lane];                   // floats 128..189
    float ss = fmaf(lo.x, lo.x, fmaf(lo.y, lo.y, fmaf(hi.x, hi.x, hi.y * hi.y)));
    #pragma unroll
    for (int off = 32; off; off >>= 1) ss += __shfl_xor(ss, off, 64);
    float2* wp = (float2*)(pf + (size_t)row * PR);
    wp[lane] = lo;                                       // slots 0..63
    if (lane < 31) wp[64 + lane] = hi;                   // slots 64..94
    if (lane == 31) wp[95] = make_float2(0.f, 0.f);      // floats 190,191 = 0
    if (lane == 0)  g_invn[row] = 1.0f / sqrtf(ss);
}

// ---------- norms only (unpadded fallback path) ----------
__global__ __launch_bounds__(256) void norms_kernel(const float* __restrict__ features) {
    const int row  = blockIdx.x * 4 + (threadIdx.x >> 6);
    const int lane = threadIdx.x & 63;
    if (row >= NTOTAL) return;
    const float2* rp = (const float2*)(features + (size_t)row * D);
    float2 a = rp[lane];
    float ss = fmaf(a.x, a.x, a.y * a.y);
    if (lane < 31) {
        float2 b = rp[64 + lane];
        ss = fmaf(b.x, b.x, fmaf(b.y, b.y, ss));
    }
    #pragma unroll
    for (int off = 32; off; off >>= 1) ss += __shfl_xor(ss, off, 64);
    if (lane == 0) g_invn[row] = 1.0f / sqrtf(ss);
}

// ---------- wa1 = W@a1, wa2 = W@a2 ----------
__global__ __launch_bounds__(192) void prep_wa(const float* __restrict__ weight,
                                               const float* __restrict__ avec) {
    const int d = threadIdx.x;              // 0..191
    float s1 = 0.f, s2 = 0.f;
    if (d < D) {
        const float* wr = weight + d * E;
        #pragma unroll 8
        for (int e = 0; e < E; ++e) {
            const float w = wr[e];
            s1 = fmaf(w, avec[e],     s1);
            s2 = fmaf(w, avec[E + e], s2);
        }
    }
    g_wa[d]       = s1;
    g_wa[192 + d] = s2;
}

// ---------- PADDED main: 4-row bursts, SGPR bases, (256,4) -> 64-VGPR alloc ----------
// hipcc's empirical behavior (R5/R6/R7/R11): allocates ~half the min-waves cap:
// (256,4)->64, (256,3)->84, (256,2)->128, (256,8)->32. The 4-row-burst +
// readfirstlane working set is ~55-60 regs -> fits 64 WITHOUT spill (unlike R5's
// 8-row burst at ~100 regs). WRITE_SIZE is the spill detector.
template <int PR>
__global__ __launch_bounds__(256, 4) void interagg_pad(
    const float* __restrict__ pf,         // [NTOTAL, PR] padded
    const int*   __restrict__ nodes,
    const int*   __restrict__ neigh1,
    const int*   __restrict__ neigh2,
    const int*   __restrict__ neigh3,
    const float* __restrict__ weight,     // [D, E]
    float*       __restrict__ out)        // [N, E]
{
    __shared__ int   s_idx[4][96];
    __shared__ float s_sim[4][32];
    __shared__ __align__(16) float s_v[4][192];

    const int t    = threadIdx.x;
    const int lane = t & 63;
    const int wave = t >> 6;
    const int n    = blockIdx.x * 4 + wave;

    int*   idxw = s_idx[wave];
    float* simw = s_sim[wave];
    float* vw   = s_v[wave];

    {
        const int v1 = (lane < 32) ? neigh1[n * K + lane] : neigh2[n * K + (lane - 32)];
        idxw[lane] = v1;
        if (lane < 32) idxw[64 + lane] = neigh3[n * K + lane];
    }

    const int  crow = nodes[n];
    const int  hs   = 64 + (lane & 31);            // hi float2 slot (64..95)
    const bool hiok = (lane < 32);
    const float2* crp = (const float2*)(pf + (size_t)crow * PR);
    float2 c0 = crp[lane];
    float2 c1 = crp[hs];
    if (!hiok) { c1.x = 0.f; c1.y = 0.f; }         // lanes 32-63: duplicates, masked

    float rlx[NREL], rly[NREL], rhx[NREL], rhy[NREL];

    #pragma unroll
    for (int rel = 0; rel < NREL; ++rel) {
        const int* idz = idxw + rel * 32;

        // ---- sims: 8 bursts of 4 rows; SGPR base per row (rid wave-uniform) ----
        #pragma unroll
        for (int b = 0; b < 8; ++b) {
            float2 va[4], vb[4];
            float  dt[4];
            #pragma unroll
            for (int i = 0; i < 4; ++i) {
                const int rid = __builtin_amdgcn_readfirstlane(idz[b * 4 + i]);
                const float2* rp = (const float2*)(pf + (size_t)rid * PR);
                va[i] = rp[lane];
                vb[i] = rp[hs];
            }
            #pragma unroll
            for (int i = 0; i < 4; ++i)
                dt[i] = fmaf(c0.x, va[i].x, fmaf(c0.y, va[i].y,
                        fmaf(c1.x, vb[i].x, c1.y * vb[i].y)));
            #pragma unroll
            for (int off = 32; off; off >>= 1) {
                #pragma unroll
                for (int i = 0; i < 4; ++i)
                    dt[i] += __shfl_xor(dt[i], off, 64);
            }
            if (lane == 0) {
                #pragma unroll
                for (int i = 0; i < 4; ++i)
                    simw[b * 4 + i] = dt[i];
            }
        }

        // ---- scale by 1/||nf||: 32 parallel per-lane gathers ----
        if (lane < 32) simw[lane] *= g_invn[idz[lane]];

        // ---- top-S by rank via shuffles (ties -> lower index, as lax.top_k) ----
        const float sk = simw[lane & 31];
        int rank = (lane < 32) ? 0 : 64;
        #pragma unroll
        for (int j = 0; j < K; ++j) {
            const float sj = __shfl(sk, j, 64);
            rank += (sj > sk) || (sj == sk && j < lane);
        }
        unsigned int m = (unsigned int)__ballot(rank < S);

        // ---- mean of 16 selected rows: 4 bursts of 4 (L2-hot re-gather) ----
        float2 acc_lo = make_float2(0.f, 0.f);
        float2 acc_hi = make_float2(0.f, 0.f);
        #pragma unroll
        for (int q = 0; q < 4; ++q) {
            float2 ua[4], ub[4];
            #pragma unroll
            for (int i = 0; i < 4; ++i) {
                const int k = __ffs(m) - 1; m &= m - 1;
                const int rid = __builtin_amdgcn_readfirstlane(idz[k]);
                const float2* rp = (const float2*)(pf + (size_t)rid * PR);
                ua[i] = rp[lane];
                ub[i] = rp[hs];
            }
            #pragma unroll
            for (int i = 0; i < 4; ++i) {
                acc_lo.x += ua[i].x; acc_lo.y += ua[i].y;
                acc_hi.x += ub[i].x; acc_hi.y += ub[i].y;
            }
        }
        rlx[rel] = fmaxf(acc_lo.x * (1.f / S), 0.f);
        rly[rel] = fmaxf(acc_lo.y * (1.f / S), 0.f);
        rhx[rel] = fmaxf(acc_hi.x * (1.f / S), 0.f);      // lanes>=32: dup data, unused
        rhy[rel] = fmaxf(acc_hi.y * (1.f / S), 0.f);
    }

    // ---- attention scores: e_r = center.wa1 + rmean_r.wa2 ----
    const float2* gw1 = (const float2*)g_wa;
    const float2* gw2 = (const float2*)(g_wa + 192);
    float2 w1l = gw1[lane];
    float2 w1h = gw1[hs];                                 // slots 190,191 = 0
    float2 w2l = gw2[lane];
    float2 w2h = gw2[hs];
    if (!hiok) { w1h.x = w1h.y = 0.f; w2h.x = w2h.y = 0.f; }

    float dv[4];
    dv[0] = fmaf(c0.x, w1l.x, fmaf(c0.y, w1l.y, fmaf(c1.x, w1h.x, c1.y * w1h.y)));
    #pragma unroll
    for (int r = 0; r < NREL; ++r)
        dv[1 + r] = fmaf(rlx[r], w2l.x, fmaf(rly[r], w2l.y,
                    fmaf(rhx[r], w2h.x, rhy[r] * w2h.y)));
    #pragma unroll
    for (int off = 32; off; off >>= 1) {
        #pragma unroll
        for (int i = 0; i < 4; ++i)
            dv[i] += __shfl_xor(dv[i], off, 64);
    }

    float e1 = dv[0] + dv[1], e2 = dv[0] + dv[2], e3 = dv[0] + dv[3];
    e1 = (e1 >= 0.f) ? e1 : 0.2f * e1;
    e2 = (e2 >= 0.f) ? e2 : 0.2f * e2;
    e3 = (e3 >= 0.f) ? e3 : 0.2f * e3;
    const float mx  = fmaxf(e1, fmaxf(e2, e3));
    const float x1 = expf(e1 - mx), x2 = expf(e2 - mx), x3 = expf(e3 - mx);
    const float inv = 1.f / (x1 + x2 + x3);
    const float a1w = x1 * inv, a2w = x2 * inv, a3w = x3 * inv;

    // ---- v = center + sum att_r * rmean_r ; out = relu(v @ W) ----
    float2 v_lo, v_hi;
    v_lo.x = fmaf(a1w, rlx[0], fmaf(a2w, rlx[1], fmaf(a3w, rlx[2], c0.x)));
    v_lo.y = fmaf(a1w, rly[0], fmaf(a2w, rly[1], fmaf(a3w, rly[2], c0.y)));
    v_hi.x = fmaf(a1w, rhx[0], fmaf(a2w, rhx[1], fmaf(a3w, rhx[2], c1.x)));
    v_hi.y = fmaf(a1w, rhy[0], fmaf(a2w, rhy[1], fmaf(a3w, rhy[2], c1.y)));

    ((float2*)vw)[lane] = v_lo;
    if (hiok) ((float2*)vw)[64 + lane] = v_hi;            // lane31 writes zeros to 190,191

    float acc = 0.f;
    const float* wcol = weight + lane;
    #pragma unroll 4
    for (int d4 = 0; d4 < 47; ++d4) {                     // dims 0..187
        const float4 vv = *((const float4*)vw + d4);      // uniform b128 broadcast
        const int d = d4 * 4;
        acc = fmaf(vv.x, wcol[(d    ) * E], acc);
        acc = fmaf(vv.y, wcol[(d + 1) * E], acc);
        acc = fmaf(vv.z, wcol[(d + 2) * E], acc);
        acc = fmaf(vv.w, wcol[(d + 3) * E], acc);
    }
    {                                                     // dims 188,189
        const float2 vv2 = *((const float2*)vw + 94);
        acc = fmaf(vv2.x, wcol[188 * E], acc);
        acc = fmaf(vv2.y, wcol[189 * E], acc);
    }
    out[(size_t)n * E + lane] = fmaxf(acc, 0.f);
}

// ---------- FALLBACK main (R8 verbatim): unpadded reads + g_invn table ----------
__global__ __launch_bounds__(256) void interagg_wave(
    const float* __restrict__ features,
    const int*   __restrict__ nodes,
    const int*   __restrict__ neigh1,
    const int*   __restrict__ neigh2,
    const int*   __restrict__ neigh3,
    const float* __restrict__ weight,
    float*       __restrict__ out)
{
    __shared__ int   s_idx[4][96];
    __shared__ float s_sim[4][32];
    __shared__ __align__(16) float s_v[4][192];

    const int t    = threadIdx.x;
    const int lane = t & 63;
    const int wave = t >> 6;
    const int n    = blockIdx.x * 4 + wave;

    int*   idxw = s_idx[wave];
    float* simw = s_sim[wave];
    float* vw   = s_v[wave];

    {
        const int v1 = (lane < 32) ? neigh1[n * K + lane] : neigh2[n * K + (lane - 32)];
        idxw[lane] = v1;
        if (lane < 32) idxw[64 + lane] = neigh3[n * K + lane];
    }

    const int  crow = nodes[n];
    const int  hl   = (lane < 31) ? lane : 30;
    const bool hiok = (lane < 31);
    const float2* crp = (const float2*)(features + (size_t)crow * D);
    float2 c0 = crp[lane];
    float2 c1 = crp[64 + hl];
    if (!hiok) { c1.x = 0.f; c1.y = 0.f; }

    float rlx[NREL], rly[NREL], rhx[NREL], rhy[NREL];

    #pragma unroll
    for (int rel = 0; rel < NREL; ++rel) {
        const int* idz = idxw + rel * 32;
        #pragma unroll
        for (int b = 0; b < 4; ++b) {
            float2 va[8], vb[8];
            float  dt[8];
            #pragma unroll
            for (int i = 0; i < 8; ++i) {
                const int rid = idz[b * 8 + i];
                const float2* rp = (const float2*)(features + (size_t)rid * D);
                va[i] = rp[lane];
                vb[i] = rp[64 + hl];
            }
            #pragma unroll
            for (int i = 0; i < 8; ++i)
                dt[i] = fmaf(c0.x, va[i].x, fmaf(c0.y, va[i].y,
                        fmaf(c1.x, vb[i].x, c1.y * vb[i].y)));
            #pragma unroll
            for (int off = 32; off; off >>= 1) {
                #pragma unroll
                for (int i = 0; i < 8; ++i)
                    dt[i] += __shfl_xor(dt[i], off, 64);
            }
            if (lane == 0) {
                #pragma unroll
                for (int i = 0; i < 8; ++i)
                    simw[b * 8 + i] = dt[i];
            }
        }
        if (lane < 32) simw[lane] *= g_invn[idz[lane]];

        const float sk = simw[lane & 31];
        int rank = (lane < 32) ? 0 : 64;
        #pragma unroll
        for (int j = 0; j < K; ++j) {
            const float sj = __shfl(sk, j, 64);
            rank += (sj > sk) || (sj == sk && j < lane);
        }
        unsigned int m = (unsigned int)__ballot(rank < S);

        float2 acc_lo = make_float2(0.f, 0.f);
        float2 acc_hi = make_float2(0.f, 0.f);
        #pragma unroll
        for (int half = 0; half < 2; ++half) {
            float2 ua[8], ub[8];
            #pragma unroll
            for (int i = 0; i < 8; ++i) {
                const int k = __ffs(m) - 1; m &= m - 1;
                const int rid = idz[k];
                const float2* rp = (const float2*)(features + (size_t)rid * D);
                ua[i] = rp[lane];
                ub[i] = rp[64 + hl];
            }
            #pragma unroll
            for (int i = 0; i < 8; ++i) {
                acc_lo.x += ua[i].x; acc_lo.y += ua[i].y;
                acc_hi.x += ub[i].x; acc_hi.y += ub[i].y;
            }
        }
        rlx[rel] = fmaxf(acc_lo.x * (1.f / S), 0.f);
        rly[rel] = fmaxf(acc_lo.y * (1.f / S), 0.f);
        rhx[rel] = fmaxf(acc_hi.x * (1.f / S), 0.f);
        rhy[rel] = fmaxf(acc_hi.y * (1.f / S), 0.f);
    }

    float2 w1l = ((const float2*)g_wa)[lane];
    float2 w1h = ((const float2*)g_wa)[64 + hl];
    float2 w2l = ((const float2*)(g_wa + 192))[lane];
    float2 w2h = ((const float2*)(g_wa + 192))[64 + hl];
    if (!hiok) { w1h.x = w1h.y = 0.f; w2h.x = w2h.y = 0.f; }

    float dv[4];
    dv[0] = fmaf(c0.x, w1l.x, fmaf(c0.y, w1l.y, fmaf(c1.x, w1h.x, c1.y * w1h.y)));
    #pragma unroll
    for (int r = 0; r < NREL; ++r)
        dv[1 + r] = fmaf(rlx[r], w2l.x, fmaf(rly[r], w2l.y,
                    fmaf(rhx[r], w2h.x, rhy[r] * w2h.y)));
    #pragma unroll
    for (int off = 32; off; off >>= 1) {
        #pragma unroll
        for (int i = 0; i < 4; ++i)
            dv[i] += __shfl_xor(dv[i], off, 64);
    }

    float e1 = dv[0] + dv[1], e2 = dv[0] + dv[2], e3 = dv[0] + dv[3];
    e1 = (e1 >= 0.f) ? e1 : 0.2f * e1;
    e2 = (e2 >= 0.f) ? e2 : 0.2f * e2;
    e3 = (e3 >= 0.f) ? e3 : 0.2f * e3;
    const float mx  = fmaxf(e1, fmaxf(e2, e3));
    const float x1 = expf(e1 - mx), x2 = expf(e2 - mx), x3 = expf(e3 - mx);
    const float inv = 1.f / (x1 + x2 + x3);
    const float a1w = x1 * inv, a2w = x2 * inv, a3w = x3 * inv;

    float2 v_lo, v_hi;
    v_lo.x = fmaf(a1w, rlx[0], fmaf(a2w, rlx[1], fmaf(a3w, rlx[2], c0.x)));
    v_lo.y = fmaf(a1w, rly[0], fmaf(a2w, rly[1], fmaf(a3w, rly[2], c0.y)));
    v_hi.x = fmaf(a1w, rhx[0], fmaf(a2w, rhx[1], fmaf(a3w, rhx[2], c1.x)));
    v_hi.y = fmaf(a1w, rhy[0], fmaf(a2w, rhy[1], fmaf(a3w, rhy[2], c1.y)));

    ((float2*)vw)[lane] = v_lo;
    if (hiok) ((float2*)vw)[64 + lane] = v_hi;

    float acc = 0.f;
    const float* wcol = weight + lane;
    #pragma unroll 4
    for (int d4 = 0; d4 < 47; ++d4) {
        const float4 vv = *((const float4*)vw + d4);
        const int d = d4 * 4;
        acc = fmaf(vv.x, wcol[(d    ) * E], acc);
        acc = fmaf(vv.y, wcol[(d + 1) * E], acc);
        acc = fmaf(vv.z, wcol[(d + 2) * E], acc);
        acc = fmaf(vv.w, wcol[(d + 3) * E], acc);
    }
    {
        const float2 vv2 = *((const float2*)vw + 94);
        acc = fmaf(vv2.x, wcol[188 * E], acc);
        acc = fmaf(vv2.y, wcol[189 * E], acc);
    }
    out[(size_t)n * E + lane] = fmaxf(acc, 0.f);
}

extern "C" void kernel_launch(void* const* d_in, const int* in_sizes, int n_in,
                              void* d_out, int out_size, void* d_ws, size_t ws_size,
                              hipStream_t stream) {
    const float* features = (const float*)d_in[0];
    const int*   nodes    = (const int*)  d_in[1];
    const int*   neigh1   = (const int*)  d_in[2];
    const int*   neigh2   = (const int*)  d_in[3];
    const int*   neigh3   = (const int*)  d_in[4];
    const float* weight   = (const float*)d_in[5];
    const float* avec     = (const float*)d_in[6];
    float*       out      = (float*)d_out;

    prep_wa<<<1, 192, 0, stream>>>(weight, avec);

    if (ws_size >= (size_t)NTOTAL * 224 * sizeof(float)) {
        // 896B stride: rows line-aligned, exactly 6 lines touched, line stride 7
        // (coprime with pow2) -> uniform L1/L2 set & channel distribution.
        float* pf = (float*)d_ws;
        pad_kernel<224><<<(NTOTAL + 3) / 4, 256, 0, stream>>>(features, pf);
        interagg_pad<224><<<NNODES / 4, 256, 0, stream>>>(
            pf, nodes, neigh1, neigh2, neigh3, weight, out);
    } else if (ws_size >= (size_t)NTOTAL * 192 * sizeof(float)) {
        float* pf = (float*)d_ws;
        pad_kernel<192><<<(NTOTAL + 3) / 4, 256, 0, stream>>>(features, pf);
        interagg_pad<192><<<NNODES / 4, 256, 0, stream>>>(
            pf, nodes, neigh1, neigh2, neigh3, weight, out);
    } else {
        norms_kernel<<<(NTOTAL + 3) / 4, 256, 0, stream>>>(features);
        interagg_wave<<<NNODES / 4, 256, 0, stream>>>(
            features, nodes, neigh1, neigh2, neigh3, weight, out);
    }
}

// Round 13
// 284.831 us; speedup vs baseline: 1.7603x; 1.3678x over previous
//
#include <hip/hip_runtime.h>

#define NTOTAL 100000
#define NNODES 16384
#define K 32
#define S 16
#define D 190
#define E 64
#define NREL 3

__device__ float g_invn[NTOTAL];
__device__ float g_wa[384];    // [0..191] = W@a1, [192..383] = W@a2 (190,191 zeroed)

// ---------- pad+norm: features -> ws rows of PR floats; invn -> g_invn ----------
template <int PR>
__global__ __launch_bounds__(256) void pad_kernel(const float* __restrict__ features,
                                                  float* __restrict__ pf) {
    const int row  = blockIdx.x * 4 + (threadIdx.x >> 6);
    const int lane = threadIdx.x & 63;
    if (row >= NTOTAL) return;
    const float2* rp = (const float2*)(features + (size_t)row * D);
    float2 lo = rp[lane];
    float2 hi = make_float2(0.f, 0.f);
    if (lane < 31) hi = rp[64 + lane];                   // floats 128..189
    float ss = fmaf(lo.x, lo.x, fmaf(lo.y, lo.y, fmaf(hi.x, hi.x, hi.y * hi.y)));
    #pragma unroll
    for (int off = 32; off; off >>= 1) ss += __shfl_xor(ss, off, 64);
    float2* wp = (float2*)(pf + (size_t)row * PR);
    wp[lane] = lo;                                       // slots 0..63
    if (lane < 31) wp[64 + lane] = hi;                   // slots 64..94
    if (lane == 31) wp[95] = make_float2(0.f, 0.f);      // floats 190,191 = 0
    if (lane == 0)  g_invn[row] = 1.0f / sqrtf(ss);
}

// ---------- norms only (unpadded fallback path) ----------
__global__ __launch_bounds__(256) void norms_kernel(const float* __restrict__ features) {
    const int row  = blockIdx.x * 4 + (threadIdx.x >> 6);
    const int lane = threadIdx.x & 63;
    if (row >= NTOTAL) return;
    const float2* rp = (const float2*)(features + (size_t)row * D);
    float2 a = rp[lane];
    float ss = fmaf(a.x, a.x, a.y * a.y);
    if (lane < 31) {
        float2 b = rp[64 + lane];
        ss = fmaf(b.x, b.x, fmaf(b.y, b.y, ss));
    }
    #pragma unroll
    for (int off = 32; off; off >>= 1) ss += __shfl_xor(ss, off, 64);
    if (lane == 0) g_invn[row] = 1.0f / sqrtf(ss);
}

// ---------- wa1 = W@a1, wa2 = W@a2 ----------
__global__ __launch_bounds__(192) void prep_wa(const float* __restrict__ weight,
                                               const float* __restrict__ avec) {
    const int d = threadIdx.x;              // 0..191
    float s1 = 0.f, s2 = 0.f;
    if (d < D) {
        const float* wr = weight + d * E;
        #pragma unroll 8
        for (int e = 0; e < E; ++e) {
            const float w = wr[e];
            s1 = fmaf(w, avec[e],     s1);
            s2 = fmaf(w, avec[E + e], s2);
        }
    }
    g_wa[d]       = s1;
    g_wa[192 + d] = s2;
}

// ---------- PADDED main: 4-row bursts, unroll-1 burst loops, (256,4)=64 VGPR ----------
// hipcc empirical law (R5/R6/R7/R11/R12): VGPR alloc ~= half the min-waves cap:
// (256,8)->32, (256,4)->64, (256,3)->84, (256,2)->128.
// R12 lesson: with the burst loop fully unrolled, the compiler software-pipelines
// ACROSS bursts (live set ~2 bursts > 64) -> 300 MB spill. `#pragma unroll 1`
// pins the live set to one burst (~45 regs). TLP (32 waves/CU) supplies the MLP
// that per-wave pipelining would have (R11/R12: rate tracks occupancy, 3.7+ TB/s).
template <int PR>
__global__ __launch_bounds__(256, 4) void interagg_pad(
    const float* __restrict__ pf,         // [NTOTAL, PR] padded
    const int*   __restrict__ nodes,
    const int*   __restrict__ neigh1,
    const int*   __restrict__ neigh2,
    const int*   __restrict__ neigh3,
    const float* __restrict__ weight,     // [D, E]
    float*       __restrict__ out)        // [N, E]
{
    __shared__ int   s_idx[4][96];
    __shared__ float s_sim[4][32];
    __shared__ __align__(16) float s_v[4][192];

    const int t    = threadIdx.x;
    const int lane = t & 63;
    const int wave = t >> 6;
    const int n    = blockIdx.x * 4 + wave;

    int*   idxw = s_idx[wave];
    float* simw = s_sim[wave];
    float* vw   = s_v[wave];

    {
        const int v1 = (lane < 32) ? neigh1[n * K + lane] : neigh2[n * K + (lane - 32)];
        idxw[lane] = v1;
        if (lane < 32) idxw[64 + lane] = neigh3[n * K + lane];
    }

    const int  crow = nodes[n];
    const int  hs   = 64 + (lane & 31);            // hi float2 slot (64..95)
    const bool hiok = (lane < 32);
    const float2* crp = (const float2*)(pf + (size_t)crow * PR);
    float2 c0 = crp[lane];
    float2 c1 = crp[hs];
    if (!hiok) { c1.x = 0.f; c1.y = 0.f; }         // lanes 32-63: duplicates, masked

    float rlx[NREL], rly[NREL], rhx[NREL], rhy[NREL];

    #pragma unroll
    for (int rel = 0; rel < NREL; ++rel) {
        const int* idz = idxw + rel * 32;

        // ---- sims: 8 bursts of 4 rows; ONE burst live at a time (unroll 1) ----
        #pragma unroll 1
        for (int b = 0; b < 8; ++b) {
            float2 va[4], vb[4];
            float  dt[4];
            #pragma unroll
            for (int i = 0; i < 4; ++i) {
                const int rid = __builtin_amdgcn_readfirstlane(idz[b * 4 + i]);
                const float2* rp = (const float2*)(pf + (size_t)rid * PR);
                va[i] = rp[lane];
                vb[i] = rp[hs];
            }
            #pragma unroll
            for (int i = 0; i < 4; ++i)
                dt[i] = fmaf(c0.x, va[i].x, fmaf(c0.y, va[i].y,
                        fmaf(c1.x, vb[i].x, c1.y * vb[i].y)));
            #pragma unroll
            for (int off = 32; off; off >>= 1) {
                #pragma unroll
                for (int i = 0; i < 4; ++i)
                    dt[i] += __shfl_xor(dt[i], off, 64);
            }
            if (lane == 0) {
                #pragma unroll
                for (int i = 0; i < 4; ++i)
                    simw[b * 4 + i] = dt[i];
            }
        }

        // ---- scale by 1/||nf||: 32 parallel per-lane gathers ----
        if (lane < 32) simw[lane] *= g_invn[idz[lane]];

        // ---- top-S by rank via shuffles (ties -> lower index, as lax.top_k) ----
        const float sk = simw[lane & 31];
        int rank = (lane < 32) ? 0 : 64;
        #pragma unroll
        for (int j = 0; j < K; ++j) {
            const float sj = __shfl(sk, j, 64);
            rank += (sj > sk) || (sj == sk && j < lane);
        }
        unsigned int m = (unsigned int)__ballot(rank < S);

        // ---- mean of 16 selected rows: 4 bursts of 4 (unroll 1, L2-hot) ----
        float2 acc_lo = make_float2(0.f, 0.f);
        float2 acc_hi = make_float2(0.f, 0.f);
        #pragma unroll 1
        for (int q = 0; q < 4; ++q) {
            float2 ua[4], ub[4];
            #pragma unroll
            for (int i = 0; i < 4; ++i) {
                const int k = __ffs(m) - 1; m &= m - 1;
                const int rid = __builtin_amdgcn_readfirstlane(idz[k]);
                const float2* rp = (const float2*)(pf + (size_t)rid * PR);
                ua[i] = rp[lane];
                ub[i] = rp[hs];
            }
            #pragma unroll
            for (int i = 0; i < 4; ++i) {
                acc_lo.x += ua[i].x; acc_lo.y += ua[i].y;
                acc_hi.x += ub[i].x; acc_hi.y += ub[i].y;
            }
        }
        rlx[rel] = fmaxf(acc_lo.x * (1.f / S), 0.f);
        rly[rel] = fmaxf(acc_lo.y * (1.f / S), 0.f);
        rhx[rel] = fmaxf(acc_hi.x * (1.f / S), 0.f);      // lanes>=32: dup data, unused
        rhy[rel] = fmaxf(acc_hi.y * (1.f / S), 0.f);
    }

    // ---- attention scores: e_r = center.wa1 + rmean_r.wa2 ----
    const float2* gw1 = (const float2*)g_wa;
    const float2* gw2 = (const float2*)(g_wa + 192);
    float2 w1l = gw1[lane];
    float2 w1h = gw1[hs];                                 // slots 190,191 = 0
    float2 w2l = gw2[lane];
    float2 w2h = gw2[hs];
    if (!hiok) { w1h.x = w1h.y = 0.f; w2h.x = w2h.y = 0.f; }

    float dv[4];
    dv[0] = fmaf(c0.x, w1l.x, fmaf(c0.y, w1l.y, fmaf(c1.x, w1h.x, c1.y * w1h.y)));
    #pragma unroll
    for (int r = 0; r < NREL; ++r)
        dv[1 + r] = fmaf(rlx[r], w2l.x, fmaf(rly[r], w2l.y,
                    fmaf(rhx[r], w2h.x, rhy[r] * w2h.y)));
    #pragma unroll
    for (int off = 32; off; off >>= 1) {
        #pragma unroll
        for (int i = 0; i < 4; ++i)
            dv[i] += __shfl_xor(dv[i], off, 64);
    }

    float e1 = dv[0] + dv[1], e2 = dv[0] + dv[2], e3 = dv[0] + dv[3];
    e1 = (e1 >= 0.f) ? e1 : 0.2f * e1;
    e2 = (e2 >= 0.f) ? e2 : 0.2f * e2;
    e3 = (e3 >= 0.f) ? e3 : 0.2f * e3;
    const float mx  = fmaxf(e1, fmaxf(e2, e3));
    const float x1 = expf(e1 - mx), x2 = expf(e2 - mx), x3 = expf(e3 - mx);
    const float inv = 1.f / (x1 + x2 + x3);
    const float a1w = x1 * inv, a2w = x2 * inv, a3w = x3 * inv;

    // ---- v = center + sum att_r * rmean_r ; out = relu(v @ W) ----
    float2 v_lo, v_hi;
    v_lo.x = fmaf(a1w, rlx[0], fmaf(a2w, rlx[1], fmaf(a3w, rlx[2], c0.x)));
    v_lo.y = fmaf(a1w, rly[0], fmaf(a2w, rly[1], fmaf(a3w, rly[2], c0.y)));
    v_hi.x = fmaf(a1w, rhx[0], fmaf(a2w, rhx[1], fmaf(a3w, rhx[2], c1.x)));
    v_hi.y = fmaf(a1w, rhy[0], fmaf(a2w, rhy[1], fmaf(a3w, rhy[2], c1.y)));

    ((float2*)vw)[lane] = v_lo;
    if (hiok) ((float2*)vw)[64 + lane] = v_hi;            // lane31 writes zeros to 190,191

    float acc = 0.f;
    const float* wcol = weight + lane;
    #pragma unroll 4
    for (int d4 = 0; d4 < 47; ++d4) {                     // dims 0..187
        const float4 vv = *((const float4*)vw + d4);      // uniform b128 broadcast
        const int d = d4 * 4;
        acc = fmaf(vv.x, wcol[(d    ) * E], acc);
        acc = fmaf(vv.y, wcol[(d + 1) * E], acc);
        acc = fmaf(vv.z, wcol[(d + 2) * E], acc);
        acc = fmaf(vv.w, wcol[(d + 3) * E], acc);
    }
    {                                                     // dims 188,189
        const float2 vv2 = *((const float2*)vw + 94);
        acc = fmaf(vv2.x, wcol[188 * E], acc);
        acc = fmaf(vv2.y, wcol[189 * E], acc);
    }
    out[(size_t)n * E + lane] = fmaxf(acc, 0.f);
}

// ---------- FALLBACK main (R8 verbatim): unpadded reads + g_invn table ----------
__global__ __launch_bounds__(256) void interagg_wave(
    const float* __restrict__ features,
    const int*   __restrict__ nodes,
    const int*   __restrict__ neigh1,
    const int*   __restrict__ neigh2,
    const int*   __restrict__ neigh3,
    const float* __restrict__ weight,
    float*       __restrict__ out)
{
    __shared__ int   s_idx[4][96];
    __shared__ float s_sim[4][32];
    __shared__ __align__(16) float s_v[4][192];

    const int t    = threadIdx.x;
    const int lane = t & 63;
    const int wave = t >> 6;
    const int n    = blockIdx.x * 4 + wave;

    int*   idxw = s_idx[wave];
    float* simw = s_sim[wave];
    float* vw   = s_v[wave];

    {
        const int v1 = (lane < 32) ? neigh1[n * K + lane] : neigh2[n * K + (lane - 32)];
        idxw[lane] = v1;
        if (lane < 32) idxw[64 + lane] = neigh3[n * K + lane];
    }

    const int  crow = nodes[n];
    const int  hl   = (lane < 31) ? lane : 30;
    const bool hiok = (lane < 31);
    const float2* crp = (const float2*)(features + (size_t)crow * D);
    float2 c0 = crp[lane];
    float2 c1 = crp[64 + hl];
    if (!hiok) { c1.x = 0.f; c1.y = 0.f; }

    float rlx[NREL], rly[NREL], rhx[NREL], rhy[NREL];

    #pragma unroll
    for (int rel = 0; rel < NREL; ++rel) {
        const int* idz = idxw + rel * 32;
        #pragma unroll
        for (int b = 0; b < 4; ++b) {
            float2 va[8], vb[8];
            float  dt[8];
            #pragma unroll
            for (int i = 0; i < 8; ++i) {
                const int rid = idz[b * 8 + i];
                const float2* rp = (const float2*)(features + (size_t)rid * D);
                va[i] = rp[lane];
                vb[i] = rp[64 + hl];
            }
            #pragma unroll
            for (int i = 0; i < 8; ++i)
                dt[i] = fmaf(c0.x, va[i].x, fmaf(c0.y, va[i].y,
                        fmaf(c1.x, vb[i].x, c1.y * vb[i].y)));
            #pragma unroll
            for (int off = 32; off; off >>= 1) {
                #pragma unroll
                for (int i = 0; i < 8; ++i)
                    dt[i] += __shfl_xor(dt[i], off, 64);
            }
            if (lane == 0) {
                #pragma unroll
                for (int i = 0; i < 8; ++i)
                    simw[b * 8 + i] = dt[i];
            }
        }
        if (lane < 32) simw[lane] *= g_invn[idz[lane]];

        const float sk = simw[lane & 31];
        int rank = (lane < 32) ? 0 : 64;
        #pragma unroll
        for (int j = 0; j < K; ++j) {
            const float sj = __shfl(sk, j, 64);
            rank += (sj > sk) || (sj == sk && j < lane);
        }
        unsigned int m = (unsigned int)__ballot(rank < S);

        float2 acc_lo = make_float2(0.f, 0.f);
        float2 acc_hi = make_float2(0.f, 0.f);
        #pragma unroll
        for (int half = 0; half < 2; ++half) {
            float2 ua[8], ub[8];
            #pragma unroll
            for (int i = 0; i < 8; ++i) {
                const int k = __ffs(m) - 1; m &= m - 1;
                const int rid = idz[k];
                const float2* rp = (const float2*)(features + (size_t)rid * D);
                ua[i] = rp[lane];
                ub[i] = rp[64 + hl];
            }
            #pragma unroll
            for (int i = 0; i < 8; ++i) {
                acc_lo.x += ua[i].x; acc_lo.y += ua[i].y;
                acc_hi.x += ub[i].x; acc_hi.y += ub[i].y;
            }
        }
        rlx[rel] = fmaxf(acc_lo.x * (1.f / S), 0.f);
        rly[rel] = fmaxf(acc_lo.y * (1.f / S), 0.f);
        rhx[rel] = fmaxf(acc_hi.x * (1.f / S), 0.f);
        rhy[rel] = fmaxf(acc_hi.y * (1.f / S), 0.f);
    }

    float2 w1l = ((const float2*)g_wa)[lane];
    float2 w1h = ((const float2*)g_wa)[64 + hl];
    float2 w2l = ((const float2*)(g_wa + 192))[lane];
    float2 w2h = ((const float2*)(g_wa + 192))[64 + hl];
    if (!hiok) { w1h.x = w1h.y = 0.f; w2h.x = w2h.y = 0.f; }

    float dv[4];
    dv[0] = fmaf(c0.x, w1l.x, fmaf(c0.y, w1l.y, fmaf(c1.x, w1h.x, c1.y * w1h.y)));
    #pragma unroll
    for (int r = 0; r < NREL; ++r)
        dv[1 + r] = fmaf(rlx[r], w2l.x, fmaf(rly[r], w2l.y,
                    fmaf(rhx[r], w2h.x, rhy[r] * w2h.y)));
    #pragma unroll
    for (int off = 32; off; off >>= 1) {
        #pragma unroll
        for (int i = 0; i < 4; ++i)
            dv[i] += __shfl_xor(dv[i], off, 64);
    }

    float e1 = dv[0] + dv[1], e2 = dv[0] + dv[2], e3 = dv[0] + dv[3];
    e1 = (e1 >= 0.f) ? e1 : 0.2f * e1;
    e2 = (e2 >= 0.f) ? e2 : 0.2f * e2;
    e3 = (e3 >= 0.f) ? e3 : 0.2f * e3;
    const float mx  = fmaxf(e1, fmaxf(e2, e3));
    const float x1 = expf(e1 - mx), x2 = expf(e2 - mx), x3 = expf(e3 - mx);
    const float inv = 1.f / (x1 + x2 + x3);
    const float a1w = x1 * inv, a2w = x2 * inv, a3w = x3 * inv;

    float2 v_lo, v_hi;
    v_lo.x = fmaf(a1w, rlx[0], fmaf(a2w, rlx[1], fmaf(a3w, rlx[2], c0.x)));
    v_lo.y = fmaf(a1w, rly[0], fmaf(a2w, rly[1], fmaf(a3w, rly[2], c0.y)));
    v_hi.x = fmaf(a1w, rhx[0], fmaf(a2w, rhx[1], fmaf(a3w, rhx[2], c1.x)));
    v_hi.y = fmaf(a1w, rhy[0], fmaf(a2w, rhy[1], fmaf(a3w, rhy[2], c1.y)));

    ((float2*)vw)[lane] = v_lo;
    if (hiok) ((float2*)vw)[64 + lane] = v_hi;

    float acc = 0.f;
    const float* wcol = weight + lane;
    #pragma unroll 4
    for (int d4 = 0; d4 < 47; ++d4) {
        const float4 vv = *((const float4*)vw + d4);
        const int d = d4 * 4;
        acc = fmaf(vv.x, wcol[(d    ) * E], acc);
        acc = fmaf(vv.y, wcol[(d + 1) * E], acc);
        acc = fmaf(vv.z, wcol[(d + 2) * E], acc);
        acc = fmaf(vv.w, wcol[(d + 3) * E], acc);
    }
    {
        const float2 vv2 = *((const float2*)vw + 94);
        acc = fmaf(vv2.x, wcol[188 * E], acc);
        acc = fmaf(vv2.y, wcol[189 * E], acc);
    }
    out[(size_t)n * E + lane] = fmaxf(acc, 0.f);
}

extern "C" void kernel_launch(void* const* d_in, const int* in_sizes, int n_in,
                              void* d_out, int out_size, void* d_ws, size_t ws_size,
                              hipStream_t stream) {
    const float* features = (const float*)d_in[0];
    const int*   nodes    = (const int*)  d_in[1];
    const int*   neigh1   = (const int*)  d_in[2];
    const int*   neigh2   = (const int*)  d_in[3];
    const int*   neigh3   = (const int*)  d_in[4];
    const float* weight   = (const float*)d_in[5];
    const float* avec     = (const float*)d_in[6];
    float*       out      = (float*)d_out;

    prep_wa<<<1, 192, 0, stream>>>(weight, avec);

    if (ws_size >= (size_t)NTOTAL * 224 * sizeof(float)) {
        // 896B stride: rows line-aligned, exactly 6 lines touched, line stride 7
        // (coprime with pow2) -> uniform L1/L2 set & channel distribution.
        float* pf = (float*)d_ws;
        pad_kernel<224><<<(NTOTAL + 3) / 4, 256, 0, stream>>>(features, pf);
        interagg_pad<224><<<NNODES / 4, 256, 0, stream>>>(
            pf, nodes, neigh1, neigh2, neigh3, weight, out);
    } else if (ws_size >= (size_t)NTOTAL * 192 * sizeof(float)) {
        float* pf = (float*)d_ws;
        pad_kernel<192><<<(NTOTAL + 3) / 4, 256, 0, stream>>>(features, pf);
        interagg_pad<192><<<NNODES / 4, 256, 0, stream>>>(
            pf, nodes, neigh1, neigh2, neigh3, weight, out);
    } else {
        norms_kernel<<<(NTOTAL + 3) / 4, 256, 0, stream>>>(features);
        interagg_wave<<<NNODES / 4, 256, 0, stream>>>(
            features, nodes, neigh1, neigh2, neigh3, weight, out);
    }
}

// Round 14
// 279.123 us; speedup vs baseline: 1.7963x; 1.0205x over previous
//
#include <hip/hip_runtime.h>

#define NTOTAL 100000
#define NNODES 16384
#define K 32
#define S 16
#define D 190
#define E 64
#define NREL 3

__device__ float g_invn[NTOTAL];
__device__ float g_wa[384];    // [0..191] = W@a1, [192..383] = W@a2 (190,191 zeroed)

// ---------- pad+norm: features -> ws rows of PR floats; invn -> g_invn ----------
template <int PR>
__global__ __launch_bounds__(256) void pad_kernel(const float* __restrict__ features,
                                                  float* __restrict__ pf) {
    const int row  = blockIdx.x * 4 + (threadIdx.x >> 6);
    const int lane = threadIdx.x & 63;
    if (row >= NTOTAL) return;
    const float2* rp = (const float2*)(features + (size_t)row * D);
    float2 lo = rp[lane];
    float2 hi = make_float2(0.f, 0.f);
    if (lane < 31) hi = rp[64 + lane];                   // floats 128..189
    float ss = fmaf(lo.x, lo.x, fmaf(lo.y, lo.y, fmaf(hi.x, hi.x, hi.y * hi.y)));
    #pragma unroll
    for (int off = 32; off; off >>= 1) ss += __shfl_xor(ss, off, 64);
    float2* wp = (float2*)(pf + (size_t)row * PR);
    wp[lane] = lo;                                       // slots 0..63
    if (lane < 31) wp[64 + lane] = hi;                   // slots 64..94
    if (lane == 31) wp[95] = make_float2(0.f, 0.f);      // floats 190,191 = 0
    if (lane == 0)  g_invn[row] = 1.0f / sqrtf(ss);
}

// ---------- norms only (unpadded fallback path) ----------
__global__ __launch_bounds__(256) void norms_kernel(const float* __restrict__ features) {
    const int row  = blockIdx.x * 4 + (threadIdx.x >> 6);
    const int lane = threadIdx.x & 63;
    if (row >= NTOTAL) return;
    const float2* rp = (const float2*)(features + (size_t)row * D);
    float2 a = rp[lane];
    float ss = fmaf(a.x, a.x, a.y * a.y);
    if (lane < 31) {
        float2 b = rp[64 + lane];
        ss = fmaf(b.x, b.x, fmaf(b.y, b.y, ss));
    }
    #pragma unroll
    for (int off = 32; off; off >>= 1) ss += __shfl_xor(ss, off, 64);
    if (lane == 0) g_invn[row] = 1.0f / sqrtf(ss);
}

// ---------- wa1 = W@a1, wa2 = W@a2 ----------
__global__ __launch_bounds__(192) void prep_wa(const float* __restrict__ weight,
                                               const float* __restrict__ avec) {
    const int d = threadIdx.x;              // 0..191
    float s1 = 0.f, s2 = 0.f;
    if (d < D) {
        const float* wr = weight + d * E;
        #pragma unroll 8
        for (int e = 0; e < E; ++e) {
            const float w = wr[e];
            s1 = fmaf(w, avec[e],     s1);
            s2 = fmaf(w, avec[E + e], s2);
        }
    }
    g_wa[d]       = s1;
    g_wa[192 + d] = s2;
}

// ---------- PADDED main: 8-row bursts (unroll 1), LDS means, (256,4)=64 VGPR ----------
// hipcc VGPR law (R5-R12): alloc ~= half the min-waves cap: (256,4)->64.
// unroll-1 on the burst loop pins the live set to ONE burst (R12/R13 lesson:
// full unroll software-pipelines across bursts -> spill). Means accumulate into
// per-wave LDS (s_rm) instead of 12 persistent VGPRs, so burst=8 (32 data regs,
// 16 loads in flight) fits the 64-reg tier. WRITE_SIZE is the spill detector.
template <int PR>
__global__ __launch_bounds__(256, 4) void interagg_pad(
    const float* __restrict__ pf,         // [NTOTAL, PR] padded
    const int*   __restrict__ nodes,
    const int*   __restrict__ neigh1,
    const int*   __restrict__ neigh2,
    const int*   __restrict__ neigh3,
    const float* __restrict__ weight,     // [D, E]
    float*       __restrict__ out)        // [N, E]
{
    __shared__ int   s_idx[4][96];
    __shared__ float s_sim[4][32];
    __shared__ __align__(16) float s_rm[4][NREL][192];   // per-wave relation means
    __shared__ __align__(16) float s_v[4][192];

    const int t    = threadIdx.x;
    const int lane = t & 63;
    const int wave = t >> 6;
    const int n    = blockIdx.x * 4 + wave;

    int*   idxw = s_idx[wave];
    float* simw = s_sim[wave];
    float* vw   = s_v[wave];

    {
        const int v1 = (lane < 32) ? neigh1[n * K + lane] : neigh2[n * K + (lane - 32)];
        idxw[lane] = v1;
        if (lane < 32) idxw[64 + lane] = neigh3[n * K + lane];
    }

    const int  crow = nodes[n];
    const int  hs   = 64 + (lane & 31);            // hi float2 slot (64..95)
    const bool hiok = (lane < 32);
    const float2* crp = (const float2*)(pf + (size_t)crow * PR);
    float2 c0 = crp[lane];
    float2 c1 = crp[hs];
    if (!hiok) { c1.x = 0.f; c1.y = 0.f; }         // lanes 32-63: duplicates, masked

    #pragma unroll 1
    for (int rel = 0; rel < NREL; ++rel) {
        const int* idz = idxw + rel * 32;

        // ---- sims: 4 bursts of 8 rows; ONE burst live at a time (unroll 1) ----
        #pragma unroll 1
        for (int b = 0; b < 4; ++b) {
            float2 va[8], vb[8];
            float  dt[8];
            #pragma unroll
            for (int i = 0; i < 8; ++i) {
                const int rid = __builtin_amdgcn_readfirstlane(idz[b * 8 + i]);
                const float2* rp = (const float2*)(pf + (size_t)rid * PR);
                va[i] = rp[lane];
                vb[i] = rp[hs];
            }
            #pragma unroll
            for (int i = 0; i < 8; ++i)
                dt[i] = fmaf(c0.x, va[i].x, fmaf(c0.y, va[i].y,
                        fmaf(c1.x, vb[i].x, c1.y * vb[i].y)));
            #pragma unroll
            for (int off = 32; off; off >>= 1) {
                #pragma unroll
                for (int i = 0; i < 8; ++i)
                    dt[i] += __shfl_xor(dt[i], off, 64);
            }
            if (lane == 0) {
                #pragma unroll
                for (int i = 0; i < 8; ++i)
                    simw[b * 8 + i] = dt[i];
            }
        }

        // ---- scale by 1/||nf||: 32 parallel per-lane gathers ----
        if (lane < 32) simw[lane] *= g_invn[idz[lane]];

        // ---- top-S by rank via shuffles (ties -> lower index, as lax.top_k) ----
        const float sk = simw[lane & 31];
        int rank = (lane < 32) ? 0 : 64;
        #pragma unroll
        for (int j = 0; j < K; ++j) {
            const float sj = __shfl(sk, j, 64);
            rank += (sj > sk) || (sj == sk && j < lane);
        }
        unsigned int m = (unsigned int)__ballot(rank < S);

        // ---- mean of 16 selected rows: 2 bursts of 8 (unroll 1, L2-hot) ----
        float2 acc_lo = make_float2(0.f, 0.f);
        float2 acc_hi = make_float2(0.f, 0.f);
        #pragma unroll 1
        for (int q = 0; q < 2; ++q) {
            float2 ua[8], ub[8];
            #pragma unroll
            for (int i = 0; i < 8; ++i) {
                const int k = __ffs(m) - 1; m &= m - 1;
                const int rid = __builtin_amdgcn_readfirstlane(idz[k]);
                const float2* rp = (const float2*)(pf + (size_t)rid * PR);
                ua[i] = rp[lane];
                ub[i] = rp[hs];
            }
            #pragma unroll
            for (int i = 0; i < 8; ++i) {
                acc_lo.x += ua[i].x; acc_lo.y += ua[i].y;
                acc_hi.x += ub[i].x; acc_hi.y += ub[i].y;
            }
        }
        // relu'd mean -> per-wave LDS (duplicate hi writes by lanes>=32 carry
        // identical values -> benign)
        float2* rm = (float2*)s_rm[wave][rel];
        rm[lane] = make_float2(fmaxf(acc_lo.x * (1.f / S), 0.f),
                               fmaxf(acc_lo.y * (1.f / S), 0.f));
        rm[hs]   = make_float2(fmaxf(acc_hi.x * (1.f / S), 0.f),
                               fmaxf(acc_hi.y * (1.f / S), 0.f));
    }

    // ---- read means back (burst regs dead now; these live only in epilogue) ----
    float rlx[NREL], rly[NREL], rhx[NREL], rhy[NREL];
    #pragma unroll
    for (int r = 0; r < NREL; ++r) {
        const float2 lo = ((const float2*)s_rm[wave][r])[lane];
        const float2 hi = ((const float2*)s_rm[wave][r])[hs];
        rlx[r] = lo.x; rly[r] = lo.y; rhx[r] = hi.x; rhy[r] = hi.y;
    }

    // ---- attention scores: e_r = center.wa1 + rmean_r.wa2 ----
    const float2* gw1 = (const float2*)g_wa;
    const float2* gw2 = (const float2*)(g_wa + 192);
    float2 w1l = gw1[lane];
    float2 w1h = gw1[hs];                                 // slots 190,191 = 0
    float2 w2l = gw2[lane];
    float2 w2h = gw2[hs];
    if (!hiok) { w1h.x = w1h.y = 0.f; w2h.x = w2h.y = 0.f; }

    float dv[4];
    dv[0] = fmaf(c0.x, w1l.x, fmaf(c0.y, w1l.y, fmaf(c1.x, w1h.x, c1.y * w1h.y)));
    #pragma unroll
    for (int r = 0; r < NREL; ++r)
        dv[1 + r] = fmaf(rlx[r], w2l.x, fmaf(rly[r], w2l.y,
                    fmaf(rhx[r], w2h.x, rhy[r] * w2h.y)));
    #pragma unroll
    for (int off = 32; off; off >>= 1) {
        #pragma unroll
        for (int i = 0; i < 4; ++i)
            dv[i] += __shfl_xor(dv[i], off, 64);
    }

    float e1 = dv[0] + dv[1], e2 = dv[0] + dv[2], e3 = dv[0] + dv[3];
    e1 = (e1 >= 0.f) ? e1 : 0.2f * e1;
    e2 = (e2 >= 0.f) ? e2 : 0.2f * e2;
    e3 = (e3 >= 0.f) ? e3 : 0.2f * e3;
    const float mx  = fmaxf(e1, fmaxf(e2, e3));
    const float x1 = expf(e1 - mx), x2 = expf(e2 - mx), x3 = expf(e3 - mx);
    const float inv = 1.f / (x1 + x2 + x3);
    const float a1w = x1 * inv, a2w = x2 * inv, a3w = x3 * inv;

    // ---- v = center + sum att_r * rmean_r ; out = relu(v @ W) ----
    float2 v_lo, v_hi;
    v_lo.x = fmaf(a1w, rlx[0], fmaf(a2w, rlx[1], fmaf(a3w, rlx[2], c0.x)));
    v_lo.y = fmaf(a1w, rly[0], fmaf(a2w, rly[1], fmaf(a3w, rly[2], c0.y)));
    v_hi.x = fmaf(a1w, rhx[0], fmaf(a2w, rhx[1], fmaf(a3w, rhx[2], c1.x)));
    v_hi.y = fmaf(a1w, rhy[0], fmaf(a2w, rhy[1], fmaf(a3w, rhy[2], c1.y)));

    ((float2*)vw)[lane] = v_lo;
    if (hiok) ((float2*)vw)[64 + lane] = v_hi;            // lane31 writes zeros to 190,191

    float acc = 0.f;
    const float* wcol = weight + lane;
    #pragma unroll 4
    for (int d4 = 0; d4 < 47; ++d4) {                     // dims 0..187
        const float4 vv = *((const float4*)vw + d4);      // uniform b128 broadcast
        const int d = d4 * 4;
        acc = fmaf(vv.x, wcol[(d    ) * E], acc);
        acc = fmaf(vv.y, wcol[(d + 1) * E], acc);
        acc = fmaf(vv.z, wcol[(d + 2) * E], acc);
        acc = fmaf(vv.w, wcol[(d + 3) * E], acc);
    }
    {                                                     // dims 188,189
        const float2 vv2 = *((const float2*)vw + 94);
        acc = fmaf(vv2.x, wcol[188 * E], acc);
        acc = fmaf(vv2.y, wcol[189 * E], acc);
    }
    out[(size_t)n * E + lane] = fmaxf(acc, 0.f);
}

// ---------- FALLBACK main (R8 verbatim): unpadded reads + g_invn table ----------
__global__ __launch_bounds__(256) void interagg_wave(
    const float* __restrict__ features,
    const int*   __restrict__ nodes,
    const int*   __restrict__ neigh1,
    const int*   __restrict__ neigh2,
    const int*   __restrict__ neigh3,
    const float* __restrict__ weight,
    float*       __restrict__ out)
{
    __shared__ int   s_idx[4][96];
    __shared__ float s_sim[4][32];
    __shared__ __align__(16) float s_v[4][192];

    const int t    = threadIdx.x;
    const int lane = t & 63;
    const int wave = t >> 6;
    const int n    = blockIdx.x * 4 + wave;

    int*   idxw = s_idx[wave];
    float* simw = s_sim[wave];
    float* vw   = s_v[wave];

    {
        const int v1 = (lane < 32) ? neigh1[n * K + lane] : neigh2[n * K + (lane - 32)];
        idxw[lane] = v1;
        if (lane < 32) idxw[64 + lane] = neigh3[n * K + lane];
    }

    const int  crow = nodes[n];
    const int  hl   = (lane < 31) ? lane : 30;
    const bool hiok = (lane < 31);
    const float2* crp = (const float2*)(features + (size_t)crow * D);
    float2 c0 = crp[lane];
    float2 c1 = crp[64 + hl];
    if (!hiok) { c1.x = 0.f; c1.y = 0.f; }

    float rlx[NREL], rly[NREL], rhx[NREL], rhy[NREL];

    #pragma unroll
    for (int rel = 0; rel < NREL; ++rel) {
        const int* idz = idxw + rel * 32;
        #pragma unroll
        for (int b = 0; b < 4; ++b) {
            float2 va[8], vb[8];
            float  dt[8];
            #pragma unroll
            for (int i = 0; i < 8; ++i) {
                const int rid = idz[b * 8 + i];
                const float2* rp = (const float2*)(features + (size_t)rid * D);
                va[i] = rp[lane];
                vb[i] = rp[64 + hl];
            }
            #pragma unroll
            for (int i = 0; i < 8; ++i)
                dt[i] = fmaf(c0.x, va[i].x, fmaf(c0.y, va[i].y,
                        fmaf(c1.x, vb[i].x, c1.y * vb[i].y)));
            #pragma unroll
            for (int off = 32; off; off >>= 1) {
                #pragma unroll
                for (int i = 0; i < 8; ++i)
                    dt[i] += __shfl_xor(dt[i], off, 64);
            }
            if (lane == 0) {
                #pragma unroll
                for (int i = 0; i < 8; ++i)
                    simw[b * 8 + i] = dt[i];
            }
        }
        if (lane < 32) simw[lane] *= g_invn[idz[lane]];

        const float sk = simw[lane & 31];
        int rank = (lane < 32) ? 0 : 64;
        #pragma unroll
        for (int j = 0; j < K; ++j) {
            const float sj = __shfl(sk, j, 64);
            rank += (sj > sk) || (sj == sk && j < lane);
        }
        unsigned int m = (unsigned int)__ballot(rank < S);

        float2 acc_lo = make_float2(0.f, 0.f);
        float2 acc_hi = make_float2(0.f, 0.f);
        #pragma unroll
        for (int half = 0; half < 2; ++half) {
            float2 ua[8], ub[8];
            #pragma unroll
            for (int i = 0; i < 8; ++i) {
                const int k = __ffs(m) - 1; m &= m - 1;
                const int rid = idz[k];
                const float2* rp = (const float2*)(features + (size_t)rid * D);
                ua[i] = rp[lane];
                ub[i] = rp[64 + hl];
            }
            #pragma unroll
            for (int i = 0; i < 8; ++i) {
                acc_lo.x += ua[i].x; acc_lo.y += ua[i].y;
                acc_hi.x += ub[i].x; acc_hi.y += ub[i].y;
            }
        }
        rlx[rel] = fmaxf(acc_lo.x * (1.f / S), 0.f);
        rly[rel] = fmaxf(acc_lo.y * (1.f / S), 0.f);
        rhx[rel] = fmaxf(acc_hi.x * (1.f / S), 0.f);
        rhy[rel] = fmaxf(acc_hi.y * (1.f / S), 0.f);
    }

    float2 w1l = ((const float2*)g_wa)[lane];
    float2 w1h = ((const float2*)g_wa)[64 + hl];
    float2 w2l = ((const float2*)(g_wa + 192))[lane];
    float2 w2h = ((const float2*)(g_wa + 192))[64 + hl];
    if (!hiok) { w1h.x = w1h.y = 0.f; w2h.x = w2h.y = 0.f; }

    float dv[4];
    dv[0] = fmaf(c0.x, w1l.x, fmaf(c0.y, w1l.y, fmaf(c1.x, w1h.x, c1.y * w1h.y)));
    #pragma unroll
    for (int r = 0; r < NREL; ++r)
        dv[1 + r] = fmaf(rlx[r], w2l.x, fmaf(rly[r], w2l.y,
                    fmaf(rhx[r], w2h.x, rhy[r] * w2h.y)));
    #pragma unroll
    for (int off = 32; off; off >>= 1) {
        #pragma unroll
        for (int i = 0; i < 4; ++i)
            dv[i] += __shfl_xor(dv[i], off, 64);
    }

    float e1 = dv[0] + dv[1], e2 = dv[0] + dv[2], e3 = dv[0] + dv[3];
    e1 = (e1 >= 0.f) ? e1 : 0.2f * e1;
    e2 = (e2 >= 0.f) ? e2 : 0.2f * e2;
    e3 = (e3 >= 0.f) ? e3 : 0.2f * e3;
    const float mx  = fmaxf(e1, fmaxf(e2, e3));
    const float x1 = expf(e1 - mx), x2 = expf(e2 - mx), x3 = expf(e3 - mx);
    const float inv = 1.f / (x1 + x2 + x3);
    const float a1w = x1 * inv, a2w = x2 * inv, a3w = x3 * inv;

    float2 v_lo, v_hi;
    v_lo.x = fmaf(a1w, rlx[0], fmaf(a2w, rlx[1], fmaf(a3w, rlx[2], c0.x)));
    v_lo.y = fmaf(a1w, rly[0], fmaf(a2w, rly[1], fmaf(a3w, rly[2], c0.y)));
    v_hi.x = fmaf(a1w, rhx[0], fmaf(a2w, rhx[1], fmaf(a3w, rhx[2], c1.x)));
    v_hi.y = fmaf(a1w, rhy[0], fmaf(a2w, rhy[1], fmaf(a3w, rhy[2], c1.y)));

    ((float2*)vw)[lane] = v_lo;
    if (hiok) ((float2*)vw)[64 + lane] = v_hi;

    float acc = 0.f;
    const float* wcol = weight + lane;
    #pragma unroll 4
    for (int d4 = 0; d4 < 47; ++d4) {
        const float4 vv = *((const float4*)vw + d4);
        const int d = d4 * 4;
        acc = fmaf(vv.x, wcol[(d    ) * E], acc);
        acc = fmaf(vv.y, wcol[(d + 1) * E], acc);
        acc = fmaf(vv.z, wcol[(d + 2) * E], acc);
        acc = fmaf(vv.w, wcol[(d + 3) * E], acc);
    }
    {
        const float2 vv2 = *((const float2*)vw + 94);
        acc = fmaf(vv2.x, wcol[188 * E], acc);
        acc = fmaf(vv2.y, wcol[189 * E], acc);
    }
    out[(size_t)n * E + lane] = fmaxf(acc, 0.f);
}

extern "C" void kernel_launch(void* const* d_in, const int* in_sizes, int n_in,
                              void* d_out, int out_size, void* d_ws, size_t ws_size,
                              hipStream_t stream) {
    const float* features = (const float*)d_in[0];
    const int*   nodes    = (const int*)  d_in[1];
    const int*   neigh1   = (const int*)  d_in[2];
    const int*   neigh2   = (const int*)  d_in[3];
    const int*   neigh3   = (const int*)  d_in[4];
    const float* weight   = (const float*)d_in[5];
    const float* avec     = (const float*)d_in[6];
    float*       out      = (float*)d_out;

    prep_wa<<<1, 192, 0, stream>>>(weight, avec);

    if (ws_size >= (size_t)NTOTAL * 224 * sizeof(float)) {
        // 896B stride: rows line-aligned, exactly 6 lines touched, line stride 7
        // (coprime with pow2) -> uniform L1/L2 set & channel distribution.
        float* pf = (float*)d_ws;
        pad_kernel<224><<<(NTOTAL + 3) / 4, 256, 0, stream>>>(features, pf);
        interagg_pad<224><<<NNODES / 4, 256, 0, stream>>>(
            pf, nodes, neigh1, neigh2, neigh3, weight, out);
    } else if (ws_size >= (size_t)NTOTAL * 192 * sizeof(float)) {
        float* pf = (float*)d_ws;
        pad_kernel<192><<<(NTOTAL + 3) / 4, 256, 0, stream>>>(features, pf);
        interagg_pad<192><<<NNODES / 4, 256, 0, stream>>>(
            pf, nodes, neigh1, neigh2, neigh3, weight, out);
    } else {
        norms_kernel<<<(NTOTAL + 3) / 4, 256, 0, stream>>>(features);
        interagg_wave<<<NNODES / 4, 256, 0, stream>>>(
            features, nodes, neigh1, neigh2, neigh3, weight, out);
    }
}